// Round 13
// baseline (54.662 us; speedup 1.0000x reference)
//
#include <hip/hip_runtime.h>
#include <hip/hip_bf16.h>

#define N_NODES   50000
#define N_EDGES   625000
#define HF        128
#define MTILE     64
#define NTILES    ((N_EDGES + MTILE - 1) / MTILE)
#define NROWTILES (N_NODES / 16)                             // 3125 exact
#define HB_BYTES  ((size_t)N_NODES * HF * sizeof(short))     // v2 fallback
#define W1F_BYTES ((size_t)4096 * 16)                        // 65,536
#define UVQ_BYTES ((size_t)N_NODES * 256)                    // 12,800,000
#define SCL_BYTES ((size_t)N_NODES * 8)                      // 400,000
#define WS_NEED   (W1F_BYTES + UVQ_BYTES + SCL_BYTES)        // ~13.27 MB

typedef __attribute__((ext_vector_type(8))) short s16x8;
typedef __attribute__((ext_vector_type(4))) float f32x4;
typedef __attribute__((ext_vector_type(4))) unsigned int u32x4;

__device__ __forceinline__ short f2bf(float x) {
    unsigned u = __builtin_bit_cast(unsigned, x);
    u += 0x7FFFu + ((u >> 16) & 1u);          // round-to-nearest-even
    return (short)(u >> 16);
}
__device__ __forceinline__ float bf2f(short s) {
    return __builtin_bit_cast(float, ((unsigned)(unsigned short)s) << 16);
}

// ---------------------------------------------------------------------------
// W -> fragment-ordered bf16. Combined B = [W1[0:128,:] | W1[128:256,:]],
// K=128, N=256 (U cols 0..127 top half of W1, V cols 128..255 bottom half).
// ---------------------------------------------------------------------------
__global__ void conv_w_kernel(const float* __restrict__ W1, short* __restrict__ w1f) {
    int j = blockIdx.x * 256 + threadIdx.x;
    if (j < 4096) {
        const int lr  = j & 15;
        const int lg  = (j >> 4) & 3;
        const int ntg = (j >> 6) & 15;
        const int kt  = j >> 10;
        const int n2  = ntg * 16 + lr;
        const int kb  = kt * 32 + lg * 8;
        const float* wp = (n2 < 128) ? (W1 + (size_t)kb * 128 + n2)
                                     : (W1 + (size_t)(kb + 128) * 128 + (n2 - 128));
        s16x8 f;
        #pragma unroll
        for (int i = 0; i < 8; ++i) f[i] = f2bf(wp[(size_t)i * 128]);
        ((s16x8*)w1f)[j] = f;
    }
}

// ---------------------------------------------------------------------------
// UV GEMM v7 (round-11 version, KNOWN GOOD — reverted from v8 to isolate
// the edge-kernel fix): weights-stationary persistent + h prefetch, int8
// quantizing epilogue (per-row amax, biased-uint8, scales to scl[]).
// ---------------------------------------------------------------------------
__global__ __launch_bounds__(256, 3) void uv_gemm7_kernel(
    const float* __restrict__ h,
    const short* __restrict__ w1f,
    const float* __restrict__ b1,
    unsigned char* __restrict__ UVq,
    float2* __restrict__ scl)
{
    __shared__ short ldsA[16 * 128];              // 4 KB bf16 A tile (swizzled)
    __shared__ float rm[4][16];                   // per-wave row maxes
    __shared__ __align__(16) char qt[16][272];    // int8 C tile (+16B pad)

    const int t  = threadIdx.x;
    const int w  = t >> 6;
    const int l  = t & 63;
    const int lg = l >> 4;
    const int lr = l & 15;
    const int srow = t >> 4;
    const int sch  = t & 15;
    const int side = w >> 1;                      // 0 = U (cols 0..127), 1 = V

    s16x8 bfrag[4][4];
    #pragma unroll
    for (int kt = 0; kt < 4; ++kt)
        #pragma unroll
        for (int nt = 0; nt < 4; ++nt)
            bfrag[kt][nt] = ((const s16x8*)w1f)[(kt * 16 + w * 4 + nt) * 64 + l];

    float b1v[4];
    #pragma unroll
    for (int nt = 0; nt < 4; ++nt)
        b1v[nt] = 0.5f * b1[(w * 64 + nt * 16 + lr) & 127];

    int tile = blockIdx.x;
    f32x4 pa, pb;
    {
        int gr = tile * 16 + srow; if (gr > N_NODES - 1) gr = N_NODES - 1;
        const float* hp = h + (size_t)gr * HF + sch * 8;
        pa = *reinterpret_cast<const f32x4*>(hp);
        pb = *reinterpret_cast<const f32x4*>(hp + 4);
    }

    while (tile < NROWTILES) {
        const int R0 = tile * 16;
        {
            s16x8 p;
            p[0]=f2bf(pa[0]); p[1]=f2bf(pa[1]); p[2]=f2bf(pa[2]); p[3]=f2bf(pa[3]);
            p[4]=f2bf(pb[0]); p[5]=f2bf(pb[1]); p[6]=f2bf(pb[2]); p[7]=f2bf(pb[3]);
            *reinterpret_cast<s16x8*>((char*)ldsA + srow * 256 + ((sch * 16) ^ ((srow & 7) << 4))) = p;
        }
        const int next = tile + gridDim.x;
        if (next < NROWTILES) {
            int gr = next * 16 + srow; if (gr > N_NODES - 1) gr = N_NODES - 1;
            const float* hp = h + (size_t)gr * HF + sch * 8;
            pa = *reinterpret_cast<const f32x4*>(hp);
            pb = *reinterpret_cast<const f32x4*>(hp + 4);
        }
        __syncthreads();

        s16x8 afr[4];
        #pragma unroll
        for (int kt = 0; kt < 4; ++kt)
            afr[kt] = *reinterpret_cast<const s16x8*>(
                (char*)ldsA + lr * 256 + ((kt * 64 + lg * 16) ^ ((lr & 7) << 4)));

        f32x4 acc[4];
        #pragma unroll
        for (int nt = 0; nt < 4; ++nt) acc[nt] = (f32x4){0.f, 0.f, 0.f, 0.f};
        #pragma unroll
        for (int kt = 0; kt < 4; ++kt)
            #pragma unroll
            for (int nt = 0; nt < 4; ++nt)
                acc[nt] = __builtin_amdgcn_mfma_f32_16x16x32_bf16(afr[kt], bfrag[kt][nt], acc[nt], 0, 0, 0);

        // ---- bias + per-row absmax (rows = lg*4+rr; reduce over 16 lr lanes) ----
        float val[4][4];                 // [nt][rr]
        float am[4];
        #pragma unroll
        for (int rr = 0; rr < 4; ++rr) am[rr] = 0.f;
        #pragma unroll
        for (int nt = 0; nt < 4; ++nt)
            #pragma unroll
            for (int rr = 0; rr < 4; ++rr) {
                float v = acc[nt][rr] + b1v[nt];
                val[nt][rr] = v;
                float a = fabsf(v);
                am[rr] = a > am[rr] ? a : am[rr];
            }
        #pragma unroll
        for (int m = 1; m <= 8; m <<= 1)
            #pragma unroll
            for (int rr = 0; rr < 4; ++rr) {
                float o = __shfl_xor(am[rr], m, 64);
                am[rr] = o > am[rr] ? o : am[rr];
            }
        if (lr == 0) {
            #pragma unroll
            for (int rr = 0; rr < 4; ++rr) rm[w][lg * 4 + rr] = am[rr];
        }
        __syncthreads();

        // ---- quantize to biased uint8, write qt ----
        #pragma unroll
        for (int rr = 0; rr < 4; ++rr) {
            const int row = lg * 4 + rr;
            const float rmax = fmaxf(rm[side * 2][row], rm[side * 2 + 1][row]);
            const float inv = rmax > 0.f ? 127.f / rmax : 0.f;
            #pragma unroll
            for (int nt = 0; nt < 4; ++nt) {
                int q = (int)rintf(val[nt][rr] * inv) + 128;
                q = q < 0 ? 0 : (q > 255 ? 255 : q);
                qt[row][w * 64 + nt * 16 + lr] = (char)q;
            }
        }
        if (t < 16) {
            const float sU = fmaxf(rm[0][t], rm[1][t]) * (1.f / 127.f);
            const float sV = fmaxf(rm[2][t], rm[3][t]) * (1.f / 127.f);
            const int grow = R0 + t;
            if (grow < N_NODES) {
                float2 s2; s2.x = sU; s2.y = sV;
                scl[grow] = s2;
            }
        }
        __syncthreads();

        // ---- coalesced 16B store of the int8 tile ----
        {
            const int row = t >> 4, ch = t & 15;
            const int grow = R0 + row;
            if (grow < N_NODES) {
                u32x4 vv = *reinterpret_cast<const u32x4*>(&qt[row][ch * 16]);
                *reinterpret_cast<u32x4*>(UVq + (size_t)grow * 256 + ch * 16) = vv;
            }
        }
        __syncthreads();
        tile = next;
    }
}

// ---------------------------------------------------------------------------
// Edge combine v8 (int8, int2-packed ids, FIXED shfl-exec hazard):
// r12's bug: `eh ? __shfl(..) : __shfl(..)` with lane-divergent eh put
// ds_bpermute under a partial exec mask -> undefined data. Fix: transpose
// the edge->iteration mapping (group eg handles edge eg*8 + k), so the
// pair component selector is k&1 — a compile-time constant — and every
// shfl executes unconditionally with full exec.
// Per edge: 16 int8 data requests (floor) + 2 scale + 1 id.
// ---------------------------------------------------------------------------
__device__ __forceinline__ float dot16q(u32x4 u, u32x4 v, float su, float sv,
                                        const float* w2) {
    const float off = -128.f * (su + sv);
    float a = 0.f;
    #pragma unroll
    for (int q = 0; q < 4; ++q) {
        const unsigned uu = u[q], vv = v[q];
        #pragma unroll
        for (int b = 0; b < 4; ++b) {
            const float cu = (float)((uu >> (8 * b)) & 255u);
            const float cv = (float)((vv >> (8 * b)) & 255u);
            float tt = fmaf(su, cu, fmaf(sv, cv, off));
            tt = tt > 0.f ? tt : 0.f;
            a = fmaf(tt, w2[q * 4 + b], a);
        }
    }
    return a;
}

__global__ __launch_bounds__(256) void edge_combine8_kernel(
    const unsigned char* __restrict__ UVq,
    const float2* __restrict__ scl,
    const int*   __restrict__ src,
    const int*   __restrict__ dst,
    const float* __restrict__ W2,
    const float* __restrict__ b2,
    float* __restrict__ out)
{
    const int t  = threadIdx.x;
    const int w  = t >> 6;
    const int l  = t & 63;
    const int eg = l >> 3;         // edge group 0..7 (handles edges eg*8+k)
    const int dg = l & 7;          // dim group 0..7 (dims dg*16..+15)

    float w2v[16];
    #pragma unroll
    for (int j = 0; j < 16; ++j) w2v[j] = W2[dg * 16 + j];
    const float b2v = b2[0];

    const int gw = blockIdx.x * 4 + w;
    const int stride = gridDim.x * 4 * 64;

    for (int base = gw * 64; base < N_EDGES; base += stride) {
        // ids as int2: lanes 0..31 -> src pairs 0..31 of this 64-edge window,
        // lanes 32..63 -> dst pairs. Pair p covers edges base+2p, base+2p+1.
        int ii = base + 2 * (l & 31);
        if (ii > N_EDGES - 2) ii = N_EDGES - 2;
        const int2 id2 = *reinterpret_cast<const int2*>(((l < 32) ? src : dst) + ii);

        // scales: lanes<32 hold sU of their src pair; lanes>=32 sV of dst pair
        const float2 sca = scl[id2.x];
        const float2 scb = scl[id2.y];
        const float sv0 = (l < 32) ? sca.x : sca.y;   // component .x node
        const float sv1 = (l < 32) ? scb.x : scb.y;   // component .y node

        #pragma unroll
        for (int k = 0; k < 8; ++k) {
            // edge e = base + eg*8 + k ; pair = eg*4 + k/2 ; component = k&1
            const int sl = eg * 4 + (k >> 1);
            const int s  = (k & 1) ? __shfl(id2.y, sl, 64)      : __shfl(id2.x, sl, 64);
            const int d  = (k & 1) ? __shfl(id2.y, 32 + sl, 64) : __shfl(id2.x, 32 + sl, 64);
            const float su = (k & 1) ? __shfl(sv1, sl, 64)      : __shfl(sv0, sl, 64);
            const float sv = (k & 1) ? __shfl(sv1, 32 + sl, 64) : __shfl(sv0, 32 + sl, 64);

            u32x4 uq = *(const u32x4*)(UVq + (size_t)s * 256 + dg * 16);
            u32x4 vq = *(const u32x4*)(UVq + (size_t)d * 256 + 128 + dg * 16);

            float a = dot16q(uq, vq, su, sv, w2v);
            a += __shfl_xor(a, 1, 64);
            a += __shfl_xor(a, 2, 64);
            a += __shfl_xor(a, 4, 64);

            const int e = base + eg * 8 + k;
            if (dg == 0 && e < N_EDGES)
                __builtin_nontemporal_store(a + b2v, &out[e]);
        }
    }
}

// ---------------------------------------------------------------------------
// v2 fallback (only if ws too small): bf16 h + direct-gather MFMA
// ---------------------------------------------------------------------------
__global__ void conv_h_kernel(const float* __restrict__ h, short* __restrict__ hb) {
    int i = blockIdx.x * blockDim.x + threadIdx.x;
    const int n8 = N_NODES * HF / 8;
    if (i < n8) {
        f32x4 a = ((const f32x4*)h)[i * 2];
        f32x4 b = ((const f32x4*)h)[i * 2 + 1];
        s16x8 p;
        p[0]=f2bf(a[0]); p[1]=f2bf(a[1]); p[2]=f2bf(a[2]); p[3]=f2bf(a[3]);
        p[4]=f2bf(b[0]); p[5]=f2bf(b[1]); p[6]=f2bf(b[2]); p[7]=f2bf(b[3]);
        ((s16x8*)hb)[i] = p;
    }
}

__device__ __forceinline__ void gatherA(const short* __restrict__ hb,
                                        int sid, int did, int lg, s16x8 (&A)[8]) {
    const s16x8* bs = (const s16x8*)(hb + (size_t)sid * HF);
    const s16x8* bd = (const s16x8*)(hb + (size_t)did * HF);
    A[0] = bs[lg];      A[1] = bs[4 + lg];  A[2] = bs[8 + lg];  A[3] = bs[12 + lg];
    A[4] = bd[lg];      A[5] = bd[4 + lg];  A[6] = bd[8 + lg];  A[7] = bd[12 + lg];
}

__device__ __forceinline__ void step_tile_v2(
    int tile, int g,
    const short* __restrict__ hb,
    const int* __restrict__ src, const int* __restrict__ dst,
    s16x8 (&Acur)[8], s16x8 (&Anext)[8],
    int sidg, int didg, int& sid2, int& did2,
    const s16x8 (&bfrag)[8][4],
    const float (&b1v)[4], const float (&w2v)[4], float b2v,
    float* __restrict__ out,
    float (&lds_p)[2][2][MTILE], int pp,
    int t, int r, int c, int lg, int lr, int myrow)
{
    gatherA(hb, sidg, didg, lg, Anext);
    {
        int e = (tile + 2 * g) * MTILE + myrow;
        e = e < N_EDGES ? e : N_EDGES - 1;
        sid2 = src[e]; did2 = dst[e];
    }
    f32x4 acc[4];
    #pragma unroll
    for (int nt = 0; nt < 4; ++nt) acc[nt] = (f32x4){0.f, 0.f, 0.f, 0.f};
    #pragma unroll
    for (int kt = 0; kt < 8; ++kt)
        #pragma unroll
        for (int nt = 0; nt < 4; ++nt)
            acc[nt] = __builtin_amdgcn_mfma_f32_16x16x32_bf16(Acur[kt], bfrag[kt][nt], acc[nt], 0, 0, 0);

    float s0[4];
    #pragma unroll
    for (int rr = 0; rr < 4; ++rr) {
        float a = 0.f;
        #pragma unroll
        for (int nt = 0; nt < 4; ++nt) {
            float v = acc[nt][rr] + b1v[nt];
            v = v > 0.f ? v : 0.f;
            a += v * w2v[nt];
        }
        s0[rr] = a;
    }
    #pragma unroll
    for (int mask = 1; mask <= 8; mask <<= 1)
        #pragma unroll
        for (int rr = 0; rr < 4; ++rr)
            s0[rr] += __shfl_xor(s0[rr], mask, 64);

    if (lr == 0) {
        #pragma unroll
        for (int rr = 0; rr < 4; ++rr)
            lds_p[pp][c][r * 16 + lg * 4 + rr] = s0[rr];
    }
    asm volatile("s_waitcnt lgkmcnt(0)" ::: "memory");
    __builtin_amdgcn_s_barrier();
    asm volatile("" ::: "memory");

    if (t < MTILE) {
        int e = tile * MTILE + t;
        if (e < N_EDGES)
            out[e] = lds_p[pp][0][t] + lds_p[pp][1][t] + b2v;
    }
}

__global__ __launch_bounds__(512, 2) void mlp_edge_score_v2(
    const short* __restrict__ hb,
    const int*   __restrict__ src,
    const int*   __restrict__ dst,
    const float* __restrict__ W1,
    const float* __restrict__ b1,
    const float* __restrict__ W2,
    const float* __restrict__ b2,
    float* __restrict__ out)
{
    __shared__ float lds_p[2][2][MTILE];

    const int t  = threadIdx.x;
    const int w  = t >> 6;
    const int l  = t & 63;
    const int r  = w >> 1;
    const int c  = w & 1;
    const int lg = l >> 4;
    const int lr = l & 15;
    const int myrow = r * 16 + lr;

    s16x8 bfrag[8][4];
    #pragma unroll
    for (int kt = 0; kt < 8; ++kt)
        #pragma unroll
        for (int nt = 0; nt < 4; ++nt) {
            const int n  = c * 64 + nt * 16 + lr;
            const int kb = kt * 32 + lg * 8;
            s16x8 f;
            #pragma unroll
            for (int i = 0; i < 8; ++i) f[i] = f2bf(W1[(size_t)(kb + i) * HF + n]);
            bfrag[kt][nt] = f;
        }
    float b1v[4], w2v[4];
    #pragma unroll
    for (int nt = 0; nt < 4; ++nt) {
        const int n = c * 64 + nt * 16 + lr;
        b1v[nt] = b1[n];
        w2v[nt] = W2[n];
    }
    const float b2v = b2[0];

    const int g = gridDim.x;
    const int tile0 = blockIdx.x;

    s16x8 Aa[8], Ab[8];
    {
        int e = tile0 * MTILE + myrow;
        e = e < N_EDGES ? e : N_EDGES - 1;
        gatherA(hb, src[e], dst[e], lg, Aa);
    }
    int sidA, didA, sidB, didB;
    {
        int e = (tile0 + g) * MTILE + myrow;
        e = e < N_EDGES ? e : N_EDGES - 1;
        sidA = src[e]; didA = dst[e];
    }

    int pp = 0;
    for (int tile = tile0; tile < NTILES; tile += 2 * g) {
        step_tile_v2(tile, g, hb, src, dst, Aa, Ab, sidA, didA, sidB, didB,
                     bfrag, b1v, w2v, b2v, out, lds_p, pp, t, r, c, lg, lr, myrow);
        pp ^= 1;
        if (tile + g < NTILES) {
            step_tile_v2(tile + g, g, hb, src, dst, Ab, Aa, sidB, didB, sidA, didA,
                         bfrag, b1v, w2v, b2v, out, lds_p, pp, t, r, c, lg, lr, myrow);
            pp ^= 1;
        }
    }
}

extern "C" void kernel_launch(void* const* d_in, const int* in_sizes, int n_in,
                              void* d_out, int out_size, void* d_ws, size_t ws_size,
                              hipStream_t stream) {
    const float* h   = (const float*)d_in[0];
    const int*   src = (const int*)  d_in[1];
    const int*   dst = (const int*)  d_in[2];
    const float* W1  = (const float*)d_in[3];
    const float* b1  = (const float*)d_in[4];
    const float* W2  = (const float*)d_in[5];
    const float* b2  = (const float*)d_in[6];
    float* out = (float*)d_out;

    if (ws_size >= WS_NEED) {
        char* ws = (char*)d_ws;
        short* w1f = (short*)ws;
        unsigned char* UVq = (unsigned char*)(ws + W1F_BYTES);
        float2* scl = (float2*)(ws + W1F_BYTES + UVQ_BYTES);

        conv_w_kernel<<<16, 256, 0, stream>>>(W1, w1f);
        uv_gemm7_kernel<<<1024, 256, 0, stream>>>(h, w1f, b1, UVq, scl);
        edge_combine8_kernel<<<1024, 256, 0, stream>>>(UVq, scl, src, dst, W2, b2, out);
    } else {
        short* hb = (short*)d_ws;
        const int n8 = N_NODES * HF / 8;
        conv_h_kernel<<<(n8 + 255) / 256, 256, 0, stream>>>(h, hb);
        mlp_edge_score_v2<<<256, 512, 0, stream>>>(hb, src, dst, W1, b1, W2, b2, out);
    }
}

// Round 14
// 47.995 us; speedup vs baseline: 1.1389x; 1.1389x over previous
//
#include <hip/hip_runtime.h>
#include <hip/hip_bf16.h>

#define N_NODES   50000
#define N_EDGES   625000
#define HF        128
#define MTILE     64
#define NTILES    ((N_EDGES + MTILE - 1) / MTILE)
#define NROWTILES (N_NODES / 16)                             // 3125 exact
#define HB_BYTES  ((size_t)N_NODES * HF * sizeof(short))     // v2 fallback
#define W1F_BYTES ((size_t)4096 * 16)                        // 65,536
#define UVQ_BYTES ((size_t)N_NODES * 256)                    // 12,800,000
#define SCL_BYTES ((size_t)N_NODES * 8)                      // 400,000
#define WS_NEED   (W1F_BYTES + UVQ_BYTES + SCL_BYTES)        // ~13.27 MB

typedef __attribute__((ext_vector_type(8))) short s16x8;
typedef __attribute__((ext_vector_type(4))) float f32x4;
typedef __attribute__((ext_vector_type(4))) unsigned int u32x4;

__device__ __forceinline__ short f2bf(float x) {
    unsigned u = __builtin_bit_cast(unsigned, x);
    u += 0x7FFFu + ((u >> 16) & 1u);          // round-to-nearest-even
    return (short)(u >> 16);
}
__device__ __forceinline__ float bf2f(short s) {
    return __builtin_bit_cast(float, ((unsigned)(unsigned short)s) << 16);
}

// ---------------------------------------------------------------------------
// W -> fragment-ordered bf16. Combined B = [W1[0:128,:] | W1[128:256,:]],
// K=128, N=256 (U cols 0..127 top half of W1, V cols 128..255 bottom half).
// ---------------------------------------------------------------------------
__global__ void conv_w_kernel(const float* __restrict__ W1, short* __restrict__ w1f) {
    int j = blockIdx.x * 256 + threadIdx.x;
    if (j < 4096) {
        const int lr  = j & 15;
        const int lg  = (j >> 4) & 3;
        const int ntg = (j >> 6) & 15;
        const int kt  = j >> 10;
        const int n2  = ntg * 16 + lr;
        const int kb  = kt * 32 + lg * 8;
        const float* wp = (n2 < 128) ? (W1 + (size_t)kb * 128 + n2)
                                     : (W1 + (size_t)(kb + 128) * 128 + (n2 - 128));
        s16x8 f;
        #pragma unroll
        for (int i = 0; i < 8; ++i) f[i] = f2bf(wp[(size_t)i * 128]);
        ((s16x8*)w1f)[j] = f;
    }
}

// ---------------------------------------------------------------------------
// UV GEMM v8: 2 barriers/tile (vs v7's 3). int8 C tile is per-wave-private
// (wave w stores its own 64-col slice), so the store phase needs only an
// lgkmcnt drain. Ordering: all ldsA reads drain by barrier-2; stage(i+1)
// happens after barrier-2(i); rm-writes(i+1) are behind barrier-1(i+1),
// which no wave passes before every wave finished quant-reads of rm(i).
// ---------------------------------------------------------------------------
__global__ __launch_bounds__(256, 3) void uv_gemm8_kernel(
    const float* __restrict__ h,
    const short* __restrict__ w1f,
    const float* __restrict__ b1,
    unsigned char* __restrict__ UVq,
    float2* __restrict__ scl)
{
    __shared__ short ldsA[16 * 128];              // 4 KB bf16 A tile (swizzled)
    __shared__ float rm[4][16];                   // per-wave row maxes
    __shared__ __align__(16) char qt[4][16][80];  // per-wave int8 slices (+pad)

    const int t  = threadIdx.x;
    const int w  = t >> 6;
    const int l  = t & 63;
    const int lg = l >> 4;
    const int lr = l & 15;
    const int srow = t >> 4;
    const int sch  = t & 15;
    const int side = w >> 1;                      // 0 = U (cols 0..127), 1 = V

    s16x8 bfrag[4][4];
    #pragma unroll
    for (int kt = 0; kt < 4; ++kt)
        #pragma unroll
        for (int nt = 0; nt < 4; ++nt)
            bfrag[kt][nt] = ((const s16x8*)w1f)[(kt * 16 + w * 4 + nt) * 64 + l];

    float b1v[4];
    #pragma unroll
    for (int nt = 0; nt < 4; ++nt)
        b1v[nt] = 0.5f * b1[(w * 64 + nt * 16 + lr) & 127];

    int tile = blockIdx.x;
    f32x4 pa, pb;
    {
        int gr = tile * 16 + srow; if (gr > N_NODES - 1) gr = N_NODES - 1;
        const float* hp = h + (size_t)gr * HF + sch * 8;
        pa = *reinterpret_cast<const f32x4*>(hp);
        pb = *reinterpret_cast<const f32x4*>(hp + 4);
    }

    while (tile < NROWTILES) {
        const int R0 = tile * 16;
        {
            s16x8 p;
            p[0]=f2bf(pa[0]); p[1]=f2bf(pa[1]); p[2]=f2bf(pa[2]); p[3]=f2bf(pa[3]);
            p[4]=f2bf(pb[0]); p[5]=f2bf(pb[1]); p[6]=f2bf(pb[2]); p[7]=f2bf(pb[3]);
            *reinterpret_cast<s16x8*>((char*)ldsA + srow * 256 + ((sch * 16) ^ ((srow & 7) << 4))) = p;
        }
        const int next = tile + gridDim.x;
        if (next < NROWTILES) {
            int gr = next * 16 + srow; if (gr > N_NODES - 1) gr = N_NODES - 1;
            const float* hp = h + (size_t)gr * HF + sch * 8;
            pa = *reinterpret_cast<const f32x4*>(hp);
            pb = *reinterpret_cast<const f32x4*>(hp + 4);
        }
        __syncthreads();                          // barrier 1: stage complete

        s16x8 afr[4];
        #pragma unroll
        for (int kt = 0; kt < 4; ++kt)
            afr[kt] = *reinterpret_cast<const s16x8*>(
                (char*)ldsA + lr * 256 + ((kt * 64 + lg * 16) ^ ((lr & 7) << 4)));

        f32x4 acc[4];
        #pragma unroll
        for (int nt = 0; nt < 4; ++nt) acc[nt] = (f32x4){0.f, 0.f, 0.f, 0.f};
        #pragma unroll
        for (int kt = 0; kt < 4; ++kt)
            #pragma unroll
            for (int nt = 0; nt < 4; ++nt)
                acc[nt] = __builtin_amdgcn_mfma_f32_16x16x32_bf16(afr[kt], bfrag[kt][nt], acc[nt], 0, 0, 0);

        // ---- bias + per-row absmax (rows = lg*4+rr; reduce over 16 lr lanes) ----
        float val[4][4];                 // [nt][rr]
        float am[4];
        #pragma unroll
        for (int rr = 0; rr < 4; ++rr) am[rr] = 0.f;
        #pragma unroll
        for (int nt = 0; nt < 4; ++nt)
            #pragma unroll
            for (int rr = 0; rr < 4; ++rr) {
                float v = acc[nt][rr] + b1v[nt];
                val[nt][rr] = v;
                float a = fabsf(v);
                am[rr] = a > am[rr] ? a : am[rr];
            }
        #pragma unroll
        for (int m = 1; m <= 8; m <<= 1)
            #pragma unroll
            for (int rr = 0; rr < 4; ++rr) {
                float o = __shfl_xor(am[rr], m, 64);
                am[rr] = o > am[rr] ? o : am[rr];
            }
        if (lr == 0) {
            #pragma unroll
            for (int rr = 0; rr < 4; ++rr) rm[w][lg * 4 + rr] = am[rr];
        }
        __syncthreads();                          // barrier 2: rm visible

        // ---- quantize to biased uint8, write per-wave qt slice ----
        #pragma unroll
        for (int rr = 0; rr < 4; ++rr) {
            const int row = lg * 4 + rr;
            const float rmax = fmaxf(rm[side * 2][row], rm[side * 2 + 1][row]);
            const float inv = rmax > 0.f ? 127.f / rmax : 0.f;
            #pragma unroll
            for (int nt = 0; nt < 4; ++nt) {
                int q = (int)rintf(val[nt][rr] * inv) + 128;
                q = q < 0 ? 0 : (q > 255 ? 255 : q);
                qt[w][row][nt * 16 + lr] = (char)q;
            }
        }
        if (t < 16) {
            const float sU = fmaxf(rm[0][t], rm[1][t]) * (1.f / 127.f);
            const float sV = fmaxf(rm[2][t], rm[3][t]) * (1.f / 127.f);
            const int grow = R0 + t;
            if (grow < N_NODES) {
                float2 s2; s2.x = sU; s2.y = sV;
                scl[grow] = s2;
            }
        }
        // wave-private slice: LDS drain only, no block barrier
        asm volatile("s_waitcnt lgkmcnt(0)" ::: "memory");

        // ---- wave-local 16B stores: lane -> (row = l>>2, chunk = l&3) ----
        {
            const int row = l >> 2, ch = l & 3;
            const int grow = R0 + row;
            if (grow < N_NODES) {
                u32x4 vv = *reinterpret_cast<const u32x4*>(&qt[w][row][ch * 16]);
                *reinterpret_cast<u32x4*>(UVq + (size_t)grow * 256 + w * 64 + ch * 16) = vv;
            }
        }
        tile = next;
    }
}

// ---------------------------------------------------------------------------
// Edge combine v6 — RESTORED VERBATIM from round 11 (measured 48.5us total).
// r13's v8 lesson: the all-gathers-issued-before-any-consume batch schedule
// is load-bearing; 2-in-flight k-loop regressed 6us. Do not restructure.
// ---------------------------------------------------------------------------
__device__ __forceinline__ float dot16q(u32x4 u, u32x4 v, float su, float sv,
                                        const float* w2) {
    const float off = -128.f * (su + sv);
    float a = 0.f;
    #pragma unroll
    for (int q = 0; q < 4; ++q) {
        const unsigned uu = u[q], vv = v[q];
        #pragma unroll
        for (int b = 0; b < 4; ++b) {
            const float cu = (float)((uu >> (8 * b)) & 255u);
            const float cv = (float)((vv >> (8 * b)) & 255u);
            float tt = fmaf(su, cu, fmaf(sv, cv, off));
            tt = tt > 0.f ? tt : 0.f;
            a = fmaf(tt, w2[q * 4 + b], a);
        }
    }
    return a;
}

__global__ __launch_bounds__(256) void edge_combine6_kernel(
    const unsigned char* __restrict__ UVq,
    const float2* __restrict__ scl,
    const int*   __restrict__ src,
    const int*   __restrict__ dst,
    const float* __restrict__ W2,
    const float* __restrict__ b2,
    float* __restrict__ out)
{
    const int t  = threadIdx.x;
    const int w  = t >> 6;
    const int l  = t & 63;
    const int eg = l >> 3;         // edge-in-sub-batch 0..7
    const int dg = l & 7;          // dim group 0..7 (dims dg*16..+15)

    float w2v[16];
    #pragma unroll
    for (int j = 0; j < 16; ++j) w2v[j] = W2[dg * 16 + j];
    const float b2v = b2[0];

    const int gw = blockIdx.x * 4 + w;
    const int stride = gridDim.x * 4 * 32;

    int base = gw * 32;
    int jj0 = base + (l & 31); if (jj0 > N_EDGES - 1) jj0 = N_EDGES - 1;
    int ids = (l < 32) ? src[jj0] : dst[jj0];

    for (; base < N_EDGES; base += stride) {
        // per-edge scales: lane<32 needs sU(src), lane>=32 needs sV(dst)
        const float2 sc2 = scl[ids];
        const float sval = (l < 32) ? sc2.x : sc2.y;

        const int s0 = __shfl(ids, 0 * 8 + eg, 64), d0 = __shfl(ids, 32 + 0 * 8 + eg, 64);
        const int s1 = __shfl(ids, 1 * 8 + eg, 64), d1 = __shfl(ids, 32 + 1 * 8 + eg, 64);
        const int s2 = __shfl(ids, 2 * 8 + eg, 64), d2 = __shfl(ids, 32 + 2 * 8 + eg, 64);
        const int s3 = __shfl(ids, 3 * 8 + eg, 64), d3 = __shfl(ids, 32 + 3 * 8 + eg, 64);

        // issue all 8 gathers (16B int8 each) before any consume
        u32x4 uq0 = *(const u32x4*)(UVq + (size_t)s0 * 256 + dg * 16);
        u32x4 vq0 = *(const u32x4*)(UVq + (size_t)d0 * 256 + 128 + dg * 16);
        u32x4 uq1 = *(const u32x4*)(UVq + (size_t)s1 * 256 + dg * 16);
        u32x4 vq1 = *(const u32x4*)(UVq + (size_t)d1 * 256 + 128 + dg * 16);
        u32x4 uq2 = *(const u32x4*)(UVq + (size_t)s2 * 256 + dg * 16);
        u32x4 vq2 = *(const u32x4*)(UVq + (size_t)d2 * 256 + 128 + dg * 16);
        u32x4 uq3 = *(const u32x4*)(UVq + (size_t)s3 * 256 + dg * 16);
        u32x4 vq3 = *(const u32x4*)(UVq + (size_t)d3 * 256 + 128 + dg * 16);

        // prefetch next iteration's ids under the gather latency
        const int nb = base + stride;
        if (nb < N_EDGES) {
            int j2 = nb + (l & 31); if (j2 > N_EDGES - 1) j2 = N_EDGES - 1;
            ids = (l < 32) ? src[j2] : dst[j2];
        }
        __builtin_amdgcn_sched_barrier(0);

        const float su0 = __shfl(sval, 0 * 8 + eg, 64), sv0 = __shfl(sval, 32 + 0 * 8 + eg, 64);
        const float su1 = __shfl(sval, 1 * 8 + eg, 64), sv1 = __shfl(sval, 32 + 1 * 8 + eg, 64);
        const float su2 = __shfl(sval, 2 * 8 + eg, 64), sv2 = __shfl(sval, 32 + 2 * 8 + eg, 64);
        const float su3 = __shfl(sval, 3 * 8 + eg, 64), sv3 = __shfl(sval, 32 + 3 * 8 + eg, 64);

        float a0 = dot16q(uq0, vq0, su0, sv0, w2v);
        float a1 = dot16q(uq1, vq1, su1, sv1, w2v);
        float a2 = dot16q(uq2, vq2, su2, sv2, w2v);
        float a3 = dot16q(uq3, vq3, su3, sv3, w2v);

        #pragma unroll
        for (int m = 1; m <= 4; m <<= 1) {
            a0 += __shfl_xor(a0, m, 64);
            a1 += __shfl_xor(a1, m, 64);
            a2 += __shfl_xor(a2, m, 64);
            a3 += __shfl_xor(a3, m, 64);
        }

        if (dg == 0) {
            if (base + 0 * 8 + eg < N_EDGES) __builtin_nontemporal_store(a0 + b2v, &out[base + 0 * 8 + eg]);
            if (base + 1 * 8 + eg < N_EDGES) __builtin_nontemporal_store(a1 + b2v, &out[base + 1 * 8 + eg]);
            if (base + 2 * 8 + eg < N_EDGES) __builtin_nontemporal_store(a2 + b2v, &out[base + 2 * 8 + eg]);
            if (base + 3 * 8 + eg < N_EDGES) __builtin_nontemporal_store(a3 + b2v, &out[base + 3 * 8 + eg]);
        }
    }
}

// ---------------------------------------------------------------------------
// v2 fallback (only if ws too small): bf16 h + direct-gather MFMA
// ---------------------------------------------------------------------------
__global__ void conv_h_kernel(const float* __restrict__ h, short* __restrict__ hb) {
    int i = blockIdx.x * blockDim.x + threadIdx.x;
    const int n8 = N_NODES * HF / 8;
    if (i < n8) {
        f32x4 a = ((const f32x4*)h)[i * 2];
        f32x4 b = ((const f32x4*)h)[i * 2 + 1];
        s16x8 p;
        p[0]=f2bf(a[0]); p[1]=f2bf(a[1]); p[2]=f2bf(a[2]); p[3]=f2bf(a[3]);
        p[4]=f2bf(b[0]); p[5]=f2bf(b[1]); p[6]=f2bf(b[2]); p[7]=f2bf(b[3]);
        ((s16x8*)hb)[i] = p;
    }
}

__device__ __forceinline__ void gatherA(const short* __restrict__ hb,
                                        int sid, int did, int lg, s16x8 (&A)[8]) {
    const s16x8* bs = (const s16x8*)(hb + (size_t)sid * HF);
    const s16x8* bd = (const s16x8*)(hb + (size_t)did * HF);
    A[0] = bs[lg];      A[1] = bs[4 + lg];  A[2] = bs[8 + lg];  A[3] = bs[12 + lg];
    A[4] = bd[lg];      A[5] = bd[4 + lg];  A[6] = bd[8 + lg];  A[7] = bd[12 + lg];
}

__device__ __forceinline__ void step_tile_v2(
    int tile, int g,
    const short* __restrict__ hb,
    const int* __restrict__ src, const int* __restrict__ dst,
    s16x8 (&Acur)[8], s16x8 (&Anext)[8],
    int sidg, int didg, int& sid2, int& did2,
    const s16x8 (&bfrag)[8][4],
    const float (&b1v)[4], const float (&w2v)[4], float b2v,
    float* __restrict__ out,
    float (&lds_p)[2][2][MTILE], int pp,
    int t, int r, int c, int lg, int lr, int myrow)
{
    gatherA(hb, sidg, didg, lg, Anext);
    {
        int e = (tile + 2 * g) * MTILE + myrow;
        e = e < N_EDGES ? e : N_EDGES - 1;
        sid2 = src[e]; did2 = dst[e];
    }
    f32x4 acc[4];
    #pragma unroll
    for (int nt = 0; nt < 4; ++nt) acc[nt] = (f32x4){0.f, 0.f, 0.f, 0.f};
    #pragma unroll
    for (int kt = 0; kt < 8; ++kt)
        #pragma unroll
        for (int nt = 0; nt < 4; ++nt)
            acc[nt] = __builtin_amdgcn_mfma_f32_16x16x32_bf16(Acur[kt], bfrag[kt][nt], acc[nt], 0, 0, 0);

    float s0[4];
    #pragma unroll
    for (int rr = 0; rr < 4; ++rr) {
        float a = 0.f;
        #pragma unroll
        for (int nt = 0; nt < 4; ++nt) {
            float v = acc[nt][rr] + b1v[nt];
            v = v > 0.f ? v : 0.f;
            a += v * w2v[nt];
        }
        s0[rr] = a;
    }
    #pragma unroll
    for (int mask = 1; mask <= 8; mask <<= 1)
        #pragma unroll
        for (int rr = 0; rr < 4; ++rr)
            s0[rr] += __shfl_xor(s0[rr], mask, 64);

    if (lr == 0) {
        #pragma unroll
        for (int rr = 0; rr < 4; ++rr)
            lds_p[pp][c][r * 16 + lg * 4 + rr] = s0[rr];
    }
    asm volatile("s_waitcnt lgkmcnt(0)" ::: "memory");
    __builtin_amdgcn_s_barrier();
    asm volatile("" ::: "memory");

    if (t < MTILE) {
        int e = tile * MTILE + t;
        if (e < N_EDGES)
            out[e] = lds_p[pp][0][t] + lds_p[pp][1][t] + b2v;
    }
}

__global__ __launch_bounds__(512, 2) void mlp_edge_score_v2(
    const short* __restrict__ hb,
    const int*   __restrict__ src,
    const int*   __restrict__ dst,
    const float* __restrict__ W1,
    const float* __restrict__ b1,
    const float* __restrict__ W2,
    const float* __restrict__ b2,
    float* __restrict__ out)
{
    __shared__ float lds_p[2][2][MTILE];

    const int t  = threadIdx.x;
    const int w  = t >> 6;
    const int l  = t & 63;
    const int r  = w >> 1;
    const int c  = w & 1;
    const int lg = l >> 4;
    const int lr = l & 15;
    const int myrow = r * 16 + lr;

    s16x8 bfrag[8][4];
    #pragma unroll
    for (int kt = 0; kt < 8; ++kt)
        #pragma unroll
        for (int nt = 0; nt < 4; ++nt) {
            const int n  = c * 64 + nt * 16 + lr;
            const int kb = kt * 32 + lg * 8;
            s16x8 f;
            #pragma unroll
            for (int i = 0; i < 8; ++i) f[i] = f2bf(W1[(size_t)(kb + i) * HF + n]);
            bfrag[kt][nt] = f;
        }
    float b1v[4], w2v[4];
    #pragma unroll
    for (int nt = 0; nt < 4; ++nt) {
        const int n = c * 64 + nt * 16 + lr;
        b1v[nt] = b1[n];
        w2v[nt] = W2[n];
    }
    const float b2v = b2[0];

    const int g = gridDim.x;
    const int tile0 = blockIdx.x;

    s16x8 Aa[8], Ab[8];
    {
        int e = tile0 * MTILE + myrow;
        e = e < N_EDGES ? e : N_EDGES - 1;
        gatherA(hb, src[e], dst[e], lg, Aa);
    }
    int sidA, didA, sidB, didB;
    {
        int e = (tile0 + g) * MTILE + myrow;
        e = e < N_EDGES ? e : N_EDGES - 1;
        sidA = src[e]; didA = dst[e];
    }

    int pp = 0;
    for (int tile = tile0; tile < NTILES; tile += 2 * g) {
        step_tile_v2(tile, g, hb, src, dst, Aa, Ab, sidA, didA, sidB, didB,
                     bfrag, b1v, w2v, b2v, out, lds_p, pp, t, r, c, lg, lr, myrow);
        pp ^= 1;
        if (tile + g < NTILES) {
            step_tile_v2(tile + g, g, hb, src, dst, Ab, Aa, sidB, didB, sidA, didA,
                         bfrag, b1v, w2v, b2v, out, lds_p, pp, t, r, c, lg, lr, myrow);
            pp ^= 1;
        }
    }
}

extern "C" void kernel_launch(void* const* d_in, const int* in_sizes, int n_in,
                              void* d_out, int out_size, void* d_ws, size_t ws_size,
                              hipStream_t stream) {
    const float* h   = (const float*)d_in[0];
    const int*   src = (const int*)  d_in[1];
    const int*   dst = (const int*)  d_in[2];
    const float* W1  = (const float*)d_in[3];
    const float* b1  = (const float*)d_in[4];
    const float* W2  = (const float*)d_in[5];
    const float* b2  = (const float*)d_in[6];
    float* out = (float*)d_out;

    if (ws_size >= WS_NEED) {
        char* ws = (char*)d_ws;
        short* w1f = (short*)ws;
        unsigned char* UVq = (unsigned char*)(ws + W1F_BYTES);
        float2* scl = (float2*)(ws + W1F_BYTES + UVQ_BYTES);

        conv_w_kernel<<<16, 256, 0, stream>>>(W1, w1f);
        uv_gemm8_kernel<<<1024, 256, 0, stream>>>(h, w1f, b1, UVq, scl);
        edge_combine6_kernel<<<1024, 256, 0, stream>>>(UVq, scl, src, dst, W2, b2, out);
    } else {
        short* hb = (short*)d_ws;
        const int n8 = N_NODES * HF / 8;
        conv_h_kernel<<<(n8 + 255) / 256, 256, 0, stream>>>(h, hb);
        mlp_edge_score_v2<<<256, 512, 0, stream>>>(hb, src, dst, W1, b1, W2, b2, out);
    }
}